// Round 7
// baseline (280.336 us; speedup 1.0000x reference)
//
#include <hip/hip_runtime.h>

// out[m,n] = sum_k x[m,k] * (qw[k,n]*scale[n]) + bias[n]
// M=8192, K=1024, N=4096 fp32. Scale factors out of K-sum -> bf16 MFMA GEMM.
//   pass1 (merged): x fp32 -> bf16 [M][K]  and  qw [K][N] fp32 -> wT [N][K] bf16
//   pass2: 256x256 GEMM, 4 single-barrier phases/K-tile, cross-phase register
//          pipelining (reads for phase q+1 issued under MFMA(q)), 3-bit XOR
//          swizzle (conflict-free ds_read_b128), counted vmcnt, setprio, XCD swizzle.

#define Mdim 8192
#define Ndim 4096
#define Kdim 1024
#define NT 16  // Kdim/64 K-tiles

typedef __attribute__((ext_vector_type(8))) short short8;
typedef __attribute__((ext_vector_type(4))) float floatx4;
typedef __attribute__((ext_vector_type(4))) unsigned short ushort4v;
typedef __attribute__((ext_vector_type(8))) unsigned short ushort8v;

__device__ inline unsigned short f2bf(float f) {
    unsigned int u = __builtin_bit_cast(unsigned int, f);
    u = (u + 0x7fffu + ((u >> 16) & 1u)) >> 16;
    return (unsigned short)u;
}

#define GLOAD_LDS16(gsrc, ldst)                                                             \
    __builtin_amdgcn_global_load_lds((const __attribute__((address_space(1))) void*)(gsrc), \
                                     (__attribute__((address_space(3))) void*)(ldst), 16, 0, 0)

// ---------------- pass 1: both conversions in one launch ----------------
__global__ __launch_bounds__(256) void cvt_kernel(const float* __restrict__ x,
                                                  const float* __restrict__ qw,
                                                  unsigned short* __restrict__ xb,
                                                  unsigned short* __restrict__ wT) {
    __shared__ unsigned short tile[64][66];
    if (blockIdx.x < 1024) {
        int bn = blockIdx.x & 63;
        int bk = blockIdx.x >> 6;
        int tx = threadIdx.x & 15;
        int ty = threadIdx.x >> 4;
        const float* src = qw + (size_t)(bk * 64) * Ndim + bn * 64 + tx * 4;
#pragma unroll
        for (int i = 0; i < 4; ++i) {
            int r = ty + i * 16;
            float4 v = *(const float4*)(src + (size_t)r * Ndim);
            tile[r][tx * 4 + 0] = f2bf(v.x);
            tile[r][tx * 4 + 1] = f2bf(v.y);
            tile[r][tx * 4 + 2] = f2bf(v.z);
            tile[r][tx * 4 + 3] = f2bf(v.w);
        }
        __syncthreads();
        unsigned short* dst = wT + (size_t)(bn * 64) * Kdim + bk * 64 + tx * 4;
#pragma unroll
        for (int i = 0; i < 4; ++i) {
            int r = ty + i * 16;
            ushort4v o;
            o[0] = tile[tx * 4 + 0][r];
            o[1] = tile[tx * 4 + 1][r];
            o[2] = tile[tx * 4 + 2][r];
            o[3] = tile[tx * 4 + 3][r];
            *(ushort4v*)(dst + (size_t)r * Kdim) = o;
        }
    } else {
        int i = (blockIdx.x - 1024) * 256 + threadIdx.x;  // exactly M*K/8 threads
        const float4* p = (const float4*)x + (size_t)i * 2;
        float4 a = p[0], b = p[1];
        ushort8v o;
        o[0] = f2bf(a.x); o[1] = f2bf(a.y); o[2] = f2bf(a.z); o[3] = f2bf(a.w);
        o[4] = f2bf(b.x); o[5] = f2bf(b.y); o[6] = f2bf(b.z); o[7] = f2bf(b.w);
        *((ushort8v*)xb + i) = o;
    }
}

// ---------------- pass 2: 256x256 pipelined GEMM ----------------
// LDS 128 KiB: [dbuf][A/B][half][128 rows x 64 k] bf16 (strides 65536/32768/16384).
// Panel row r -> half (r>>6)&1, rowInHalf (r&63)+(r>>7)*64.
// 3-bit XOR swizzle: phys = logical ^ ((logical>>3)&0x70)  (row bits 0-2 -> byte
// bits 4-6). Quarter-wave then covers all 8 16B-slots 2-way => conflict-free.
// Phase q: barrier; [prefetch frags for q+1; issue one gload half-tile; 16 MFMA].
// Staging guard: vmcnt(4)+barrier at ph3 entry (t+1 fully staged before its
// ph0 frags are prefetched). No lgkm drains: compiler inserts fine-grained waits.
__global__ __launch_bounds__(512, 2) void gemm8_kernel(const unsigned short* __restrict__ xb,
                                                       const unsigned short* __restrict__ wT,
                                                       const float* __restrict__ scales,
                                                       const float* __restrict__ bias,
                                                       float* __restrict__ out) {
    extern __shared__ char ldsc[];

    // XCD-bijective swizzle: nwg = 512, 512 % 8 == 0
    int bid = blockIdx.x;
    int swz = (bid & 7) * 64 + (bid >> 3);
    int tile_n = swz & 15;   // fast: neighbors share A panel in L2
    int tile_m = swz >> 4;

    int tid = threadIdx.x;
    int wid = tid >> 6, lane = tid & 63;
    int wr = wid >> 2, wc = wid & 3;     // wave -> (128 rows, 64 cols) sub-tile
    int la = lane & 15, lq = lane >> 4;

    // ---- staging source offsets (shorts, rel. to half's base row); dest stays linear ----
    int goffs[2];
#pragma unroll
    for (int i = 0; i < 2; ++i) {
        int d = i * 8192 + wid * 1024 + lane * 16;     // physical byte in half
        int L = d ^ ((d >> 3) & 0x70);                 // logical byte (involution)
        int rih = L >> 7, cb = L & 127;
        int grow = rih + (rih & 64);                   // undo bit6 interleave
        goffs[i] = grow * Kdim + (cb >> 1);
    }
    const unsigned short* aTile = xb + (size_t)tile_m * 256 * Kdim;
    const unsigned short* bTile = wT + (size_t)tile_n * 256 * Kdim;

    auto ISSUE = [&](int t, int op, int h) {   // one half-tile = 2 x global_load_lds16
        if (t >= NT) return;
        const unsigned short* gb = (op ? bTile : aTile) + (size_t)h * (64 * Kdim) + t * 64;
        char* ld = ldsc + (t & 1) * 65536 + op * 32768 + h * 16384 + wid * 1024;
        GLOAD_LDS16(gb + goffs[0], ld);
        GLOAD_LDS16(gb + goffs[1], ld + 8192);
    };

    // ---- ds_read addressing (swizzle pre-folded) ----
    int ca0 = (lq * 16) ^ ((la & 7) << 4);   // slot = lq ^ (la&7): 8 slots, 2 lanes each
    int ca1 = ca0 ^ 64;
    int aoff = wr * 8192 + la * 128;
    int boff = (wc >> 1) * 8192 + la * 128;

    floatx4 acc[8][4] = {};
    short8 afX[2][2], afY[2][2], bfE[4][2], bfO[4][2];

#define RD_A(DST, base, Q)                                                                  \
    _Pragma("unroll") for (int m2 = 0; m2 < 2; ++m2) {                                      \
        DST[m2][0] = *(const short8*)((base) + ((Q) >> 1) * 16384 + ((Q) & 1) * 4096 +      \
                                      m2 * 2048 + aoff + ca0);                              \
        DST[m2][1] = *(const short8*)((base) + ((Q) >> 1) * 16384 + ((Q) & 1) * 4096 +      \
                                      m2 * 2048 + aoff + ca1);                              \
    }
#define RD_B(DST, base)                                                                     \
    _Pragma("unroll") for (int ni = 0; ni < 4; ++ni) {                                      \
        DST[ni][0] = *(const short8*)((base) + ni * 2048 + boff + ca0);                     \
        DST[ni][1] = *(const short8*)((base) + ni * 2048 + boff + ca1);                     \
    }
#define MM(Q, AF, BF)                                                                       \
    _Pragma("unroll") for (int kk = 0; kk < 2; ++kk)                                        \
    _Pragma("unroll") for (int m2 = 0; m2 < 2; ++m2)                                        \
    _Pragma("unroll") for (int ni = 0; ni < 4; ++ni)                                        \
        acc[(Q) * 2 + m2][ni] = __builtin_amdgcn_mfma_f32_16x16x32_bf16(                    \
            AF[m2][kk], BF[ni][kk], acc[(Q) * 2 + m2][ni], 0, 0, 0);

#define TILE(t, BUF, BC, BNX)                                                               \
    {                                                                                       \
        const char* ab = ldsc + (BUF) * 65536;                                              \
        const char* bb = ab + 32768 + (wc & 1) * 16384;                                     \
        const char* abn = ldsc + (1 - (BUF)) * 65536;                                       \
        const char* bbn = abn + 32768 + (wc & 1) * 16384;                                   \
        /* ph0: prefetch A q1; MFMA q0 */                                                   \
        __builtin_amdgcn_s_barrier();                                                       \
        __builtin_amdgcn_s_setprio(1);                                                      \
        RD_A(afY, ab, 1);                                                                   \
        ISSUE((t) + 1, 0, 1);                                                               \
        MM(0, afX, BC);                                                                     \
        __builtin_amdgcn_s_setprio(0);                                                      \
        __builtin_amdgcn_sched_barrier(0);                                                  \
        /* ph1: prefetch A q2; MFMA q1 */                                                   \
        __builtin_amdgcn_s_barrier();                                                       \
        __builtin_amdgcn_s_setprio(1);                                                      \
        RD_A(afX, ab, 2);                                                                   \
        ISSUE((t) + 2, 1, 0);                                                               \
        MM(1, afY, BC);                                                                     \
        __builtin_amdgcn_s_setprio(0);                                                      \
        __builtin_amdgcn_sched_barrier(0);                                                  \
        /* ph2: prefetch A q3; MFMA q2 */                                                   \
        __builtin_amdgcn_s_barrier();                                                       \
        __builtin_amdgcn_s_setprio(1);                                                      \
        RD_A(afY, ab, 3);                                                                   \
        ISSUE((t) + 2, 0, 0);                                                               \
        MM(2, afX, BC);                                                                     \
        __builtin_amdgcn_s_setprio(0);                                                      \
        __builtin_amdgcn_sched_barrier(0);                                                  \
        /* ph3: staging sync for t+1; prefetch next tile ph0 frags; MFMA q3 */              \
        if ((t) < NT - 2) asm volatile("s_waitcnt vmcnt(4)" ::: "memory");                  \
        else              asm volatile("s_waitcnt vmcnt(0)" ::: "memory");                  \
        __builtin_amdgcn_s_barrier();                                                       \
        __builtin_amdgcn_s_setprio(1);                                                      \
        if ((t) + 1 < NT) { RD_A(afX, abn, 0); RD_B(BNX, bbn); }                            \
        ISSUE((t) + 2, 1, 1);                                                               \
        MM(3, afY, BC);                                                                     \
        __builtin_amdgcn_s_setprio(0);                                                      \
        __builtin_amdgcn_sched_barrier(0);                                                  \
    }

    // ---- prologue: stage t0 fully + t1 {B0,A0,B1}; wait t0; read tile0 ph0 frags ----
    ISSUE(0, 1, 0); ISSUE(0, 0, 0); ISSUE(0, 1, 1); ISSUE(0, 0, 1);
    ISSUE(1, 1, 0); ISSUE(1, 0, 0); ISSUE(1, 1, 1);
    asm volatile("s_waitcnt vmcnt(6)" ::: "memory");
    __builtin_amdgcn_s_barrier();
    RD_A(afX, ldsc, 0);
    RD_B(bfE, ldsc + 32768 + (wc & 1) * 16384);

#pragma unroll 1
    for (int t = 0; t < NT; t += 2) {
        TILE(t, 0, bfE, bfO);
        TILE(t + 1, 1, bfO, bfE);
    }

    // ---- epilogue: out = acc * scale[n] + bias[n] ----
    size_t m_base = (size_t)tile_m * 256 + wr * 128;
    int n_base = tile_n * 256 + wc * 64;
#pragma unroll
    for (int ni = 0; ni < 4; ++ni) {
        int col = n_base + ni * 16 + la;
        float s = scales[col], bb2 = bias[col];
#pragma unroll
        for (int mi = 0; mi < 8; ++mi) {
            size_t row0 = m_base + mi * 16 + lq * 4;
#pragma unroll
            for (int v = 0; v < 4; ++v)
                out[(row0 + v) * Ndim + col] = acc[mi][ni][v] * s + bb2;
        }
    }
#undef RD_A
#undef RD_B
#undef MM
#undef TILE
}

// ---------------- fallback ----------------
__global__ __launch_bounds__(256) void fallback_kernel(const float* __restrict__ x,
                                                       const float* __restrict__ qw,
                                                       const float* __restrict__ scales,
                                                       const float* __restrict__ bias,
                                                       float* __restrict__ out) {
    size_t idx = (size_t)blockIdx.x * 256 + threadIdx.x;
    size_t m = idx / Ndim, n = idx % Ndim;
    float sum = 0.f;
    for (int k = 0; k < Kdim; ++k) sum += x[m * Kdim + k] * qw[(size_t)k * Ndim + n];
    out[idx] = sum * scales[n] + bias[n];
}

extern "C" void kernel_launch(void* const* d_in, const int* in_sizes, int n_in,
                              void* d_out, int out_size, void* d_ws, size_t ws_size,
                              hipStream_t stream) {
    const float* x = (const float*)d_in[0];
    const float* qw = (const float*)d_in[1];
    const float* scales = (const float*)d_in[2];
    const float* bias = (const float*)d_in[3];
    float* out = (float*)d_out;

    size_t need = (size_t)Mdim * Kdim * 2 + (size_t)Ndim * Kdim * 2;  // 24 MB
    if (ws_size < need) {
        fallback_kernel<<<(Mdim * (size_t)Ndim) / 256, 256, 0, stream>>>(x, qw, scales, bias, out);
        return;
    }

    unsigned short* xb = (unsigned short*)d_ws;
    unsigned short* wT = xb + (size_t)Mdim * Kdim;

    (void)hipFuncSetAttribute((const void*)gemm8_kernel,
                              hipFuncAttributeMaxDynamicSharedMemorySize, 131072);

    cvt_kernel<<<1024 + Mdim * Kdim / (8 * 256), 256, 0, stream>>>(x, qw, xb, wT);
    gemm8_kernel<<<(Mdim / 256) * (Ndim / 256), 512, 131072, stream>>>(xb, wT, scales, bias, out);
}

// Round 9
// 234.462 us; speedup vs baseline: 1.1957x; 1.1957x over previous
//
#include <hip/hip_runtime.h>

// out[m,n] = sum_k x[m,k] * (qw[k,n]*scale[n]) + bias[n]
// M=8192, K=1024, N=4096 fp32. Scale factors out of K-sum -> bf16 MFMA GEMM.
//   pass1 (merged): x fp32 -> bf16 [M][K]  and  qw [K][N] fp32 -> wT [N][K] bf16
//   pass2: 256x256 8-phase GEMM (R2 structure, measured 96 us) with the
//          hardware-validated 3-bit XOR swizzle (R4 measured BANK_CONFLICT=0).
//          ONLY the swizzle differs from the 96-us R2 baseline.

#define Mdim 8192
#define Ndim 4096
#define Kdim 1024
#define NT 16  // Kdim/64 K-tiles

typedef __attribute__((ext_vector_type(8))) short short8;
typedef __attribute__((ext_vector_type(4))) float floatx4;
typedef __attribute__((ext_vector_type(4))) unsigned short ushort4v;
typedef __attribute__((ext_vector_type(8))) unsigned short ushort8v;

__device__ inline unsigned short f2bf(float f) {
    unsigned int u = __builtin_bit_cast(unsigned int, f);
    u = (u + 0x7fffu + ((u >> 16) & 1u)) >> 16;
    return (unsigned short)u;
}

#define GLOAD_LDS16(gsrc, ldst)                                                             \
    __builtin_amdgcn_global_load_lds((const __attribute__((address_space(1))) void*)(gsrc), \
                                     (__attribute__((address_space(3))) void*)(ldst), 16, 0, 0)

// ---------------- pass 1: both conversions in one launch ----------------
__global__ __launch_bounds__(256) void cvt_kernel(const float* __restrict__ x,
                                                  const float* __restrict__ qw,
                                                  unsigned short* __restrict__ xb,
                                                  unsigned short* __restrict__ wT) {
    __shared__ unsigned short tile[64][66];
    if (blockIdx.x < 1024) {
        int bn = blockIdx.x & 63;
        int bk = blockIdx.x >> 6;
        int tx = threadIdx.x & 15;
        int ty = threadIdx.x >> 4;
        const float* src = qw + (size_t)(bk * 64) * Ndim + bn * 64 + tx * 4;
#pragma unroll
        for (int i = 0; i < 4; ++i) {
            int r = ty + i * 16;
            float4 v = *(const float4*)(src + (size_t)r * Ndim);
            tile[r][tx * 4 + 0] = f2bf(v.x);
            tile[r][tx * 4 + 1] = f2bf(v.y);
            tile[r][tx * 4 + 2] = f2bf(v.z);
            tile[r][tx * 4 + 3] = f2bf(v.w);
        }
        __syncthreads();
        unsigned short* dst = wT + (size_t)(bn * 64) * Kdim + bk * 64 + tx * 4;
#pragma unroll
        for (int i = 0; i < 4; ++i) {
            int r = ty + i * 16;
            ushort4v o;
            o[0] = tile[tx * 4 + 0][r];
            o[1] = tile[tx * 4 + 1][r];
            o[2] = tile[tx * 4 + 2][r];
            o[3] = tile[tx * 4 + 3][r];
            *(ushort4v*)(dst + (size_t)r * Kdim) = o;
        }
    } else {
        int i = (blockIdx.x - 1024) * 256 + threadIdx.x;  // exactly M*K/8 threads
        const float4* p = (const float4*)x + (size_t)i * 2;
        float4 a = p[0], b = p[1];
        ushort8v o;
        o[0] = f2bf(a.x); o[1] = f2bf(a.y); o[2] = f2bf(a.z); o[3] = f2bf(a.w);
        o[4] = f2bf(b.x); o[5] = f2bf(b.y); o[6] = f2bf(b.z); o[7] = f2bf(b.w);
        *((ushort8v*)xb + i) = o;
    }
}

// ---------------- pass 2: 256x256 8-phase GEMM (R2 structure + 3-bit swizzle) ----------
// LDS 128 KiB: [dbuf][A/B][half][128 rows x 64 k] bf16 (strides 65536/32768/16384).
// Panel row r -> half (r>>6)&1, rowInHalf (r&63)+(r>>7)*64 (bit-6 split).
// 3-bit XOR swizzle (R4-validated, BANK_CONFLICT=0): phys = logical ^
// ((logical>>3)&0x70) -- row bits 0-2 XOR into byte bits 4-6. Involution,
// applied to stage SOURCE (LDS dest linear) and ds_read address.
__global__ __launch_bounds__(512, 2) void gemm8_kernel(const unsigned short* __restrict__ xb,
                                                       const unsigned short* __restrict__ wT,
                                                       const float* __restrict__ scales,
                                                       const float* __restrict__ bias,
                                                       float* __restrict__ out) {
    extern __shared__ char ldsc[];

    // XCD-bijective swizzle: nwg = 512, 512 % 8 == 0
    int bid = blockIdx.x;
    int swz = (bid & 7) * 64 + (bid >> 3);
    int tile_n = swz & 15;   // fast: neighbors share A panel in L2
    int tile_m = swz >> 4;

    int tid = threadIdx.x;
    int wid = tid >> 6, lane = tid & 63;
    int wr = wid >> 2, wc = wid & 3;     // wave -> (128 rows, 64 cols) sub-tile
    int la = lane & 15, lq = lane >> 4;

    // ---- staging source offsets (shorts, rel. to half's base row); dest stays linear ----
    int goffs[2];
#pragma unroll
    for (int i = 0; i < 2; ++i) {
        int d = i * 8192 + wid * 1024 + lane * 16;     // physical byte in half
        int L = d ^ ((d >> 3) & 0x70);                 // logical byte (3-bit involution)
        int rih = L >> 7, cb = L & 127;
        int grow = rih + (rih & 64);                   // undo bit6 interleave
        goffs[i] = grow * Kdim + (cb >> 1);
    }
    const unsigned short* aTile = xb + (size_t)tile_m * 256 * Kdim;
    const unsigned short* bTile = wT + (size_t)tile_n * 256 * Kdim;

    auto ISSUE = [&](int t, int op, int h) {   // one half-tile = 2 x global_load_lds16
        if (t >= NT) return;
        const unsigned short* gb = (op ? bTile : aTile) + (size_t)h * (64 * Kdim) + t * 64;
        char* ld = ldsc + (t & 1) * 65536 + op * 32768 + h * 16384 + wid * 1024;
        GLOAD_LDS16(gb + goffs[0], ld);
        GLOAD_LDS16(gb + goffs[1], ld + 8192);
    };

    // ---- ds_read addressing: row byte + 3-bit-swizzled col byte ----
    int ca0 = (lq * 16) ^ ((la & 7) << 4);   // slot = lq ^ (la&7): 8 slots, 2 lanes each
    int ca1 = ca0 ^ 64;                      // kk*64 commutes with the XOR (bit 6 flip)
    int arow = (wr * 64 + la) * 128;
    int brow = ((wc >> 1) * 64 + la) * 128;

    floatx4 acc[8][4] = {};
    short8 af[2][2], bfr[4][2];

#define LOAD_A(Q)                                                                          \
    _Pragma("unroll") for (int m2 = 0; m2 < 2; ++m2) {                                     \
        af[m2][0] = *(const short8*)(abase + ((Q) >> 1) * 16384 + ((Q) & 1) * 4096 +       \
                                     m2 * 2048 + arow + ca0);                              \
        af[m2][1] = *(const short8*)(abase + ((Q) >> 1) * 16384 + ((Q) & 1) * 4096 +       \
                                     m2 * 2048 + arow + ca1);                              \
    }
#define LOAD_B()                                                                           \
    _Pragma("unroll") for (int ni = 0; ni < 4; ++ni) {                                     \
        bfr[ni][0] = *(const short8*)(bbase + ni * 2048 + brow + ca0);                     \
        bfr[ni][1] = *(const short8*)(bbase + ni * 2048 + brow + ca1);                     \
    }
#define MFMA_PHASE(Q)                                                                      \
    _Pragma("unroll") for (int kk = 0; kk < 2; ++kk)                                       \
    _Pragma("unroll") for (int m2 = 0; m2 < 2; ++m2)                                       \
    _Pragma("unroll") for (int ni = 0; ni < 4; ++ni)                                       \
        acc[(Q)*2 + m2][ni] = __builtin_amdgcn_mfma_f32_16x16x32_bf16(                     \
            af[m2][kk], bfr[ni][kk], acc[(Q)*2 + m2][ni], 0, 0, 0);
#define SYNC_PRE                                            \
    __builtin_amdgcn_s_barrier();                           \
    asm volatile("s_waitcnt lgkmcnt(0)" ::: "memory");      \
    __builtin_amdgcn_s_setprio(1);
#define SYNC_POST                                           \
    __builtin_amdgcn_s_setprio(0);                          \
    __builtin_amdgcn_s_barrier();

    // ---- prologue: tile0 all 4 halves + tile1 first 3; wait tile0 (8 loads), keep 6 in flight
    ISSUE(0, 1, 0); ISSUE(0, 0, 0); ISSUE(0, 1, 1); ISSUE(0, 0, 1);
    ISSUE(1, 1, 0); ISSUE(1, 0, 0); ISSUE(1, 1, 1);
    asm volatile("s_waitcnt vmcnt(6)" ::: "memory");
    __builtin_amdgcn_s_barrier();

#pragma unroll 1
    for (int t = 0; t < NT; ++t) {
        const char* abase = ldsc + (t & 1) * 65536;
        const char* bbase = ldsc + (t & 1) * 65536 + 32768 + (wc & 1) * 16384;

        // phase 0: all B frags + A quarter 0; replace other-buf A1 (consumed last tile ph2/3)
        LOAD_B(); LOAD_A(0);
        ISSUE(t + 1, 0, 1);
        SYNC_PRE; MFMA_PHASE(0); SYNC_POST;
        // phase 1: A quarter 1; replace this-buf B0 (B fully consumed at phase 0)
        LOAD_A(1);
        ISSUE(t + 2, 1, 0);
        SYNC_PRE; MFMA_PHASE(1); SYNC_POST;
        // phase 2: A quarter 2; replace this-buf A0 (quarters 0,1 consumed)
        LOAD_A(2);
        ISSUE(t + 2, 0, 0);
        SYNC_PRE; MFMA_PHASE(2); SYNC_POST;
        // phase 3: A quarter 3; replace this-buf B1; per-K-tile counted vmcnt
        LOAD_A(3);
        ISSUE(t + 2, 1, 1);
        SYNC_PRE; MFMA_PHASE(3);
        __builtin_amdgcn_s_setprio(0);
        if (t < NT - 2)       asm volatile("s_waitcnt vmcnt(6)" ::: "memory");
        else if (t == NT - 2) asm volatile("s_waitcnt vmcnt(0)" ::: "memory");
        __builtin_amdgcn_s_barrier();
    }

    // ---- epilogue: out = acc * scale[n] + bias[n] ----
    size_t m_base = (size_t)tile_m * 256 + wr * 128;
    int n_base = tile_n * 256 + wc * 64;
#pragma unroll
    for (int ni = 0; ni < 4; ++ni) {
        int col = n_base + ni * 16 + la;
        float s = scales[col], bb2 = bias[col];
#pragma unroll
        for (int mi = 0; mi < 8; ++mi) {
            size_t row0 = m_base + mi * 16 + lq * 4;
#pragma unroll
            for (int v = 0; v < 4; ++v)
                out[(row0 + v) * Ndim + col] = acc[mi][ni][v] * s + bb2;
        }
    }
#undef LOAD_A
#undef LOAD_B
#undef MFMA_PHASE
#undef SYNC_PRE
#undef SYNC_POST
}

// ---------------- fallback ----------------
__global__ __launch_bounds__(256) void fallback_kernel(const float* __restrict__ x,
                                                       const float* __restrict__ qw,
                                                       const float* __restrict__ scales,
                                                       const float* __restrict__ bias,
                                                       float* __restrict__ out) {
    size_t idx = (size_t)blockIdx.x * 256 + threadIdx.x;
    size_t m = idx / Ndim, n = idx % Ndim;
    float sum = 0.f;
    for (int k = 0; k < Kdim; ++k) sum += x[m * Kdim + k] * qw[(size_t)k * Ndim + n];
    out[idx] = sum * scales[n] + bias[n];
}

extern "C" void kernel_launch(void* const* d_in, const int* in_sizes, int n_in,
                              void* d_out, int out_size, void* d_ws, size_t ws_size,
                              hipStream_t stream) {
    const float* x = (const float*)d_in[0];
    const float* qw = (const float*)d_in[1];
    const float* scales = (const float*)d_in[2];
    const float* bias = (const float*)d_in[3];
    float* out = (float*)d_out;

    size_t need = (size_t)Mdim * Kdim * 2 + (size_t)Ndim * Kdim * 2;  // 24 MB
    if (ws_size < need) {
        fallback_kernel<<<(Mdim * (size_t)Ndim) / 256, 256, 0, stream>>>(x, qw, scales, bias, out);
        return;
    }

    unsigned short* xb = (unsigned short*)d_ws;
    unsigned short* wT = xb + (size_t)Mdim * Kdim;

    (void)hipFuncSetAttribute((const void*)gemm8_kernel,
                              hipFuncAttributeMaxDynamicSharedMemorySize, 131072);

    cvt_kernel<<<1024 + Mdim * Kdim / (8 * 256), 256, 0, stream>>>(x, qw, xb, wT);
    gemm8_kernel<<<(Mdim / 256) * (Ndim / 256), 512, 131072, stream>>>(xb, wT, scales, bias, out);
}